// Round 4
// baseline (455.702 us; speedup 1.0000x reference)
//
#include <hip/hip_runtime.h>
#include <hip/hip_fp16.h>

#define N_NODES 100000
#define IN_CH 128
#define OUT_CH 64
#define HID 128
#define N_EDGES 1600000

#define NBUCK 196               // dst >> 9, max 99999>>9 = 195
#define BBLK  512               // binning blocks (2 per CU)
#define CHUNK (N_EDGES / BBLK)  // 3125 edges per binning block
#define NH    (NBUCK * BBLK)    // 100352 histogram entries

// slice-major fp16 feature layout: [4 slices][N_NODES][32 ch]
// 32 ch * 2 B = 64 B row = EXACTLY one cache line per edge-gather (zero line waste).
// slice = blockIdx & 3 under %8 XCD round-robin -> XCD x always serves slice x&3;
// two XCDs co-serve each slice (per-XCD request load halves again).
#define SLICE ((size_t)N_NODES * 32)   // halfs per slice
#define AGG_NB (N_NODES / 16)          // 6250 blocks per slice, 16 nodes per block (exact)

typedef _Float16 half8 __attribute__((ext_vector_type(8)));
typedef float floatx4 __attribute__((ext_vector_type(4)));

// ---------------- pass 1: per-(bucket,block) histogram (LDS atomics; fully overwrites hist) ----

__global__ __launch_bounds__(256) void k_hist(const int* __restrict__ dst, int* __restrict__ hist) {
    __shared__ int lh[NBUCK];
    int t = threadIdx.x;
    int blk = blockIdx.x;
    if (t < NBUCK) lh[t] = 0;
    __syncthreads();
    int base = blk * CHUNK;
    for (int i = base + t; i < base + CHUNK; i += 256) {
        atomicAdd(&lh[dst[i] >> 9], 1);
    }
    __syncthreads();
    if (t < NBUCK) hist[t * BBLK + blk] = lh[t];
}

// ---------------- hierarchical exclusive scan (hist only) ----------------

#define SCAN_T 1024
__global__ void k_scan_local(const int* __restrict__ in, int* __restrict__ excl,
                             int* __restrict__ bsum, int n) {
    __shared__ int tmp[SCAN_T];
    int t = threadIdx.x;
    int i = blockIdx.x * SCAN_T + t;
    int v = (i < n) ? in[i] : 0;
    tmp[t] = v;
    __syncthreads();
    for (int off = 1; off < SCAN_T; off <<= 1) {
        int u = (t >= off) ? tmp[t - off] : 0;
        __syncthreads();
        tmp[t] += u;
        __syncthreads();
    }
    if (i < n) excl[i] = tmp[t] - v;
    if (t == SCAN_T - 1) bsum[blockIdx.x] = tmp[t];
}

__global__ void k_scan_sums(const int* __restrict__ bsum, int* __restrict__ boff, int nb) {
    __shared__ int tmp[128];
    int t = threadIdx.x;
    int v = (t < nb) ? bsum[t] : 0;
    tmp[t] = v;
    __syncthreads();
    for (int off = 1; off < 128; off <<= 1) {
        int u = (t >= off) ? tmp[t - off] : 0;
        __syncthreads();
        tmp[t] += u;
        __syncthreads();
    }
    if (t < nb) boff[t] = tmp[t] - v;
}

__global__ void k_scan_add1(const int* __restrict__ excl, const int* __restrict__ boff,
                            int* __restrict__ out, int n) {
    int i = blockIdx.x * blockDim.x + threadIdx.x;
    if (i < n) out[i] = excl[i] + boff[i / SCAN_T];
}

// ---------------- pass 2: scatter edges into bucket-partitioned array ----------------

__global__ __launch_bounds__(256) void k_binscatter(const int* __restrict__ src,
                                                    const int* __restrict__ dst,
                                                    const int* __restrict__ off,
                                                    int2* __restrict__ binned) {
    __shared__ int loff[NBUCK];
    int t = threadIdx.x;
    int blk = blockIdx.x;
    if (t < NBUCK) loff[t] = off[t * BBLK + blk];
    __syncthreads();
    int base = blk * CHUNK;
    for (int i = base + t; i < base + CHUNK; i += 256) {
        int d = dst[i];
        int s = src[i];
        int pos = atomicAdd(&loff[d >> 9], 1);
        binned[pos] = make_int2(s, d);
    }
}

// ---------------- pass 3: per-bucket degree/scan/fill entirely in LDS ----------------
// Produces row_start (with sentinel), dinv, csr_src. Zero global atomics.

__global__ __launch_bounds__(256) void k_bucket(const int2* __restrict__ binned,
                                                const int* __restrict__ off,
                                                int* __restrict__ row_start,
                                                float* __restrict__ dinv,
                                                int* __restrict__ csr_src) {
    __shared__ int cnt[512];
    __shared__ int ps[256];
    __shared__ int cur[512];
    int b = blockIdx.x;
    int t = threadIdx.x;
    int start = off[b * BBLK];
    int end = (b + 1 < NBUCK) ? off[(b + 1) * BBLK] : N_EDGES;
    cnt[t] = 0;
    cnt[t + 256] = 0;
    if (b == NBUCK - 1 && t == 0) row_start[N_NODES] = N_EDGES;  // sentinel
    __syncthreads();
    for (int i = start + t; i < end; i += 256) {
        atomicAdd(&cnt[binned[i].y & 511], 1);
    }
    __syncthreads();
    int a0 = cnt[2 * t], a1 = cnt[2 * t + 1];
    ps[t] = a0 + a1;
    __syncthreads();
    for (int o = 1; o < 256; o <<= 1) {
        int u = (t >= o) ? ps[t - o] : 0;
        __syncthreads();
        ps[t] += u;
        __syncthreads();
    }
    int pe = ps[t] - (a0 + a1);
    int e0 = start + pe;
    int e1 = e0 + a0;
    cur[2 * t] = e0;
    cur[2 * t + 1] = e1;
    int node0 = (b << 9) + 2 * t;
    if (node0 < N_NODES) {
        row_start[node0] = e0;
        dinv[node0] = rsqrtf((float)(a0 + 1));
    }
    if (node0 + 1 < N_NODES) {
        row_start[node0 + 1] = e1;
        dinv[node0 + 1] = rsqrtf((float)(a1 + 1));
    }
    __syncthreads();
    for (int i = start + t; i < end; i += 256) {
        int2 e = binned[i];
        int p = atomicAdd(&cur[e.y & 511], 1);
        csr_src[p] = e.x;
    }
}

// ---------------- cast + pre-scale into SLICE-MAJOR [4][N][32] layout, + folded weight prep ----
// blocks < 12500: xs[slice][node][32] = fp16(dinv[node] * x[node][slice*32+c])
// blocks >= 12500: W1t[n][k] = W1[k][n]; Wct[n][k] = (n<64 ? Wmu[k][n] : Wls[k][n-64])

__global__ __launch_bounds__(256) void k_cast_prep(const float* __restrict__ in,
                                                   const float* __restrict__ dinv,
                                                   __half* __restrict__ out,
                                                   const float* __restrict__ W1,
                                                   const float* __restrict__ Wmu,
                                                   const float* __restrict__ Wls,
                                                   __half* __restrict__ W1t,
                                                   __half* __restrict__ Wct) {
    int blk = blockIdx.x;
    int t = threadIdx.x;
    if (blk >= 12500) {  // weight prep tail blocks (64 blocks x 256 = 16384)
        int i = (blk - 12500) * 256 + t;
        if (i < 128 * 128) {
            int n = i >> 7, k = i & 127;
            W1t[i] = __float2half(W1[k * 128 + n]);
            Wct[i] = __float2half(n < 64 ? Wmu[k * 64 + n] : Wls[k * 64 + (n - 64)]);
        }
        return;
    }
    int i = blk * 256 + t;  // over float4 groups, 32 per row; 12500*256 = N_NODES*32 exact
    float4 v = ((const float4*)in)[i];
    int node = i >> 5, ch4 = i & 31;  // ch4 = which float4 group (4 channels)
    float d = dinv[node];
    // half2 units: slice = ch4>>3, node stride = 16 half2, within = (ch4&7)*2
    size_t o = (size_t)(ch4 >> 3) * (SLICE / 2) + (size_t)node * 16 + (size_t)(ch4 & 7) * 2;
    ((__half2*)out)[o]     = __floats2half2_rn(d * v.x, d * v.y);
    ((__half2*)out)[o + 1] = __floats2half2_rn(d * v.z, d * v.w);
}

// ---------------- aggregation, XCD-sliced, one-line-per-edge ----------------
// in/out slice-major [4][N][32] fp16, pre-scaled by dinv[src]. 64-B rows = 1 line per gather.
// Wave = 4 node-groups x 16 ch-lanes (half2). Per-node loop uniform across its 16 lanes
// (divergence only across the 4 groups, ~1.2x). Unroll-8 -> 32 lines in flight per wave.
// csr_src read non-temporally (streamed; don't evict the 6.4 MB gather table from L2).

__global__ __launch_bounds__(256) void k_aggs(const __half* __restrict__ in, __half* __restrict__ out,
                                              const int* __restrict__ csr_src,
                                              const int* __restrict__ row_start,
                                              const float* __restrict__ dinv) {
    int slice = blockIdx.x & 3;
    int nb = blockIdx.x >> 2;                 // 0..6249
    const __half* ins = in + (size_t)slice * SLICE;
    __half* outs = out + (size_t)slice * SLICE;
    int t = threadIdx.x;
    int lane = t & 63;
    int g = lane >> 4;                        // node sub-group 0..3
    int ch2 = (lane & 15) * 2;                // half offset within 32-ch row
    int w = nb * 16 + (t >> 6) * 4 + g;       // this group's node (6250*16 = N exact)
    int beg = row_start[w];
    int cnt = row_start[w + 1] - beg;
    float di = dinv[w];
    const int* __restrict__ cp = csr_src + beg;
    float2 self = __half22float2(*(const __half2*)(ins + (size_t)w * 32 + ch2));
    float ax = self.x, ay = self.y;
    int j = 0;
    for (; j + 7 < cnt; j += 8) {
        int s0 = __builtin_nontemporal_load(cp + j);
        int s1 = __builtin_nontemporal_load(cp + j + 1);
        int s2 = __builtin_nontemporal_load(cp + j + 2);
        int s3 = __builtin_nontemporal_load(cp + j + 3);
        int s4 = __builtin_nontemporal_load(cp + j + 4);
        int s5 = __builtin_nontemporal_load(cp + j + 5);
        int s6 = __builtin_nontemporal_load(cp + j + 6);
        int s7 = __builtin_nontemporal_load(cp + j + 7);
        float2 v0 = __half22float2(*(const __half2*)(ins + (size_t)s0 * 32 + ch2));
        float2 v1 = __half22float2(*(const __half2*)(ins + (size_t)s1 * 32 + ch2));
        float2 v2 = __half22float2(*(const __half2*)(ins + (size_t)s2 * 32 + ch2));
        float2 v3 = __half22float2(*(const __half2*)(ins + (size_t)s3 * 32 + ch2));
        float2 v4 = __half22float2(*(const __half2*)(ins + (size_t)s4 * 32 + ch2));
        float2 v5 = __half22float2(*(const __half2*)(ins + (size_t)s5 * 32 + ch2));
        float2 v6 = __half22float2(*(const __half2*)(ins + (size_t)s6 * 32 + ch2));
        float2 v7 = __half22float2(*(const __half2*)(ins + (size_t)s7 * 32 + ch2));
        ax += v0.x + v1.x + v2.x + v3.x + v4.x + v5.x + v6.x + v7.x;
        ay += v0.y + v1.y + v2.y + v3.y + v4.y + v5.y + v6.y + v7.y;
    }
    for (; j + 3 < cnt; j += 4) {
        int s0 = __builtin_nontemporal_load(cp + j);
        int s1 = __builtin_nontemporal_load(cp + j + 1);
        int s2 = __builtin_nontemporal_load(cp + j + 2);
        int s3 = __builtin_nontemporal_load(cp + j + 3);
        float2 v0 = __half22float2(*(const __half2*)(ins + (size_t)s0 * 32 + ch2));
        float2 v1 = __half22float2(*(const __half2*)(ins + (size_t)s1 * 32 + ch2));
        float2 v2 = __half22float2(*(const __half2*)(ins + (size_t)s2 * 32 + ch2));
        float2 v3 = __half22float2(*(const __half2*)(ins + (size_t)s3 * 32 + ch2));
        ax += v0.x + v1.x + v2.x + v3.x;
        ay += v0.y + v1.y + v2.y + v3.y;
    }
    for (; j < cnt; j++) {
        int s0 = __builtin_nontemporal_load(cp + j);
        float2 v0 = __half22float2(*(const __half2*)(ins + (size_t)s0 * 32 + ch2));
        ax += v0.x;
        ay += v0.y;
    }
    ax *= di;
    ay *= di;
    *(__half2*)(outs + (size_t)w * 32 + ch2) = __floats2half2_rn(ax, ay);
}

// ---------------- GEMM1 (MFMA): H = dinv * relu_normalize(relu(A @ W1 + b1)) ----------------
// A is slice-major [4][N][32]. block = 64 rows (4 waves x 16), N=128 (8 tiles), K=128 (4 steps of 32).
// A-frag k-range kk*32+quad*8..+8 lies entirely in slice kk at row offset quad*8 (no straddle);
// a wave's 64 lanes cover rows [base,base+16) x 64 B = 1 KB contiguous -> line-efficient.
// Output H written slice-major for the next k_aggs: ch n=tt*16+m16 -> slice tt>>1, within (tt&1)*16+m16.

__global__ __launch_bounds__(256) void k_gemm1(const __half* __restrict__ A,
                                               const __half* __restrict__ Wt,
                                               const float* __restrict__ b,
                                               const float* __restrict__ dinv,
                                               __half* __restrict__ H) {
    int t = threadIdx.x;
    int wv = t >> 6;
    int lane = t & 63;
    int m16 = lane & 15;
    int quad = lane >> 4;
    int row = blockIdx.x * 64 + wv * 16 + m16;
    floatx4 acc[8];
    #pragma unroll
    for (int tt = 0; tt < 8; tt++) acc[tt] = (floatx4){0.f, 0.f, 0.f, 0.f};
    #pragma unroll
    for (int kk = 0; kk < 4; kk++) {
        half8 a = *(const half8*)(A + (size_t)kk * SLICE + (size_t)row * 32 + quad * 8);
        #pragma unroll
        for (int tt = 0; tt < 8; tt++) {
            half8 bf = *(const half8*)(Wt + (size_t)(tt * 16 + m16) * 128 + kk * 32 + quad * 8);
            acc[tt] = __builtin_amdgcn_mfma_f32_16x16x32_f16(a, bf, acc[tt], 0, 0, 0);
        }
    }
    float bias[8];
    #pragma unroll
    for (int tt = 0; tt < 8; tt++) bias[tt] = b[tt * 16 + m16];
    int rbase = blockIdx.x * 64 + wv * 16 + quad * 4;
    #pragma unroll
    for (int r = 0; r < 4; r++) {
        int rw = rbase + r;
        float vv[8];
        float ssq = 0.f;
        #pragma unroll
        for (int tt = 0; tt < 8; tt++) {
            float v = fmaxf(acc[tt][r] + bias[tt], 0.f);
            vv[tt] = v;
            ssq += v * v;
        }
        ssq += __shfl_xor(ssq, 1, 64);
        ssq += __shfl_xor(ssq, 2, 64);
        ssq += __shfl_xor(ssq, 4, 64);
        ssq += __shfl_xor(ssq, 8, 64);
        float s = 1.0f / fmaxf(sqrtf(ssq), 1e-12f);
        if (rw < N_NODES) {
            float sc = s * dinv[rw];  // pre-scale for the next aggregation
            #pragma unroll
            for (int tt = 0; tt < 8; tt++) {
                H[(size_t)(tt >> 1) * SLICE + (size_t)rw * 32 + (tt & 1) * 16 + m16] =
                    __float2half(vv[tt] * sc);
            }
        }
    }
}

// ---------------- GEMM2 (MFMA): out = [ Y2@Wmu+bmu | Y2@Wls+bls ] ----------------
// A slice-major [4][N][32]; output row-major f32 (harness layout).

__global__ __launch_bounds__(256) void k_gemm2(const __half* __restrict__ A,
                                               const __half* __restrict__ Wt,
                                               const float* __restrict__ bmu,
                                               const float* __restrict__ bls,
                                               float* __restrict__ out) {
    int t = threadIdx.x;
    int wv = t >> 6;
    int lane = t & 63;
    int m16 = lane & 15;
    int quad = lane >> 4;
    int row = blockIdx.x * 64 + wv * 16 + m16;
    floatx4 acc[8];
    #pragma unroll
    for (int tt = 0; tt < 8; tt++) acc[tt] = (floatx4){0.f, 0.f, 0.f, 0.f};
    #pragma unroll
    for (int kk = 0; kk < 4; kk++) {
        half8 a = *(const half8*)(A + (size_t)kk * SLICE + (size_t)row * 32 + quad * 8);
        #pragma unroll
        for (int tt = 0; tt < 8; tt++) {
            half8 bf = *(const half8*)(Wt + (size_t)(tt * 16 + m16) * 128 + kk * 32 + quad * 8);
            acc[tt] = __builtin_amdgcn_mfma_f32_16x16x32_f16(a, bf, acc[tt], 0, 0, 0);
        }
    }
    float bias[8];
    #pragma unroll
    for (int tt = 0; tt < 8; tt++)
        bias[tt] = (tt < 4) ? bmu[tt * 16 + m16] : bls[(tt - 4) * 16 + m16];
    int rbase = blockIdx.x * 64 + wv * 16 + quad * 4;
    #pragma unroll
    for (int r = 0; r < 4; r++) {
        int rw = rbase + r;
        if (rw < N_NODES) {
            #pragma unroll
            for (int tt = 0; tt < 4; tt++)
                out[(size_t)rw * 64 + tt * 16 + m16] = acc[tt][r] + bias[tt];
            #pragma unroll
            for (int tt = 4; tt < 8; tt++)
                out[(size_t)N_NODES * 64 + (size_t)rw * 64 + (tt - 4) * 16 + m16] = acc[tt][r] + bias[tt];
        }
    }
}

// ---------------- launch ----------------

extern "C" void kernel_launch(void* const* d_in, const int* in_sizes, int n_in,
                              void* d_out, int out_size, void* d_ws, size_t ws_size,
                              hipStream_t stream) {
    const float* x   = (const float*)d_in[0];
    const int*  eidx = (const int*)d_in[1];
    const float* W1  = (const float*)d_in[2];
    const float* b1  = (const float*)d_in[3];
    const float* Wmu = (const float*)d_in[4];
    const float* bmu = (const float*)d_in[5];
    const float* Wls = (const float*)d_in[6];
    const float* bls = (const float*)d_in[7];
    float* out = (float*)d_out;
    const int* e_src = eidx;
    const int* e_dst = eidx + N_EDGES;

    char* ws = (char*)d_ws;
    size_t off_b = 0;
    auto alloc = [&](size_t n) -> void* {
        void* p = ws + off_b;
        off_b += (n + 255) & ~(size_t)255;
        return p;
    };
    float*  dinv      = (float*)alloc((size_t)N_NODES * sizeof(float));
    int*    row_start = (int*)alloc((size_t)(N_NODES + 1) * sizeof(int));
    int*    hist      = (int*)alloc((size_t)NH * sizeof(int));
    int*    excl2     = (int*)alloc((size_t)NH * sizeof(int));
    int*    bsum2     = (int*)alloc(1024 * sizeof(int));
    int*    boff2     = (int*)alloc(1024 * sizeof(int));
    int*    offs      = (int*)alloc((size_t)NH * sizeof(int));
    int*    csr_src   = (int*)alloc((size_t)N_EDGES * sizeof(int));
    int2*   binned    = (int2*)alloc((size_t)N_EDGES * sizeof(int2));
    __half* W1t       = (__half*)alloc((size_t)128 * 128 * sizeof(__half));
    __half* Wct       = (__half*)alloc((size_t)128 * 128 * sizeof(__half));
    __half* xs        = (__half*)alloc((size_t)N_NODES * IN_CH * sizeof(__half));  // also reused as bufB (y2)
    __half* bufA      = (__half*)alloc((size_t)N_NODES * HID * sizeof(__half));    // y1
    __half* bufH      = (__half*)alloc((size_t)N_NODES * HID * sizeof(__half));    // hs = dinv*h
    alloc(32 * 1024);  // pad for OOB tile reads in last GEMM block
    __half* bufB = xs;  // xs is dead after agg1; reuse for y2

    const int NB_SCAN2 = (NH + SCAN_T - 1) / SCAN_T;  // 98
    const int NGEMM = (N_NODES + 63) / 64;            // 1563

    // CSR build: hist -> scan -> binscatter -> bucket (produces row_start, dinv, csr_src)
    hipLaunchKernelGGL(k_hist, dim3(BBLK), dim3(256), 0, stream, e_dst, hist);
    hipLaunchKernelGGL(k_scan_local, dim3(NB_SCAN2), dim3(SCAN_T), 0, stream, hist, excl2, bsum2, NH);
    hipLaunchKernelGGL(k_scan_sums, dim3(1), dim3(128), 0, stream, bsum2, boff2, NB_SCAN2);
    hipLaunchKernelGGL(k_scan_add1, dim3((NH + 255) / 256), dim3(256), 0, stream, excl2, boff2, offs, NH);
    hipLaunchKernelGGL(k_binscatter, dim3(BBLK), dim3(256), 0, stream, e_src, e_dst, offs, binned);
    hipLaunchKernelGGL(k_bucket, dim3(NBUCK), dim3(256), 0, stream, binned, offs, row_start, dinv, csr_src);
    // xs = fp16(dinv * x) slice-major, + folded weight prep (needs dinv)
    hipLaunchKernelGGL(k_cast_prep, dim3(12500 + 64), dim3(256), 0, stream, x, dinv, xs,
                       W1, Wmu, Wls, W1t, Wct);
    // layer 1
    hipLaunchKernelGGL(k_aggs, dim3(4 * AGG_NB), dim3(256), 0, stream, xs, bufA, csr_src, row_start, dinv);
    hipLaunchKernelGGL(k_gemm1, dim3(NGEMM), dim3(256), 0, stream, bufA, W1t, b1, dinv, bufH);
    // shared aggregation for layers 2+3
    hipLaunchKernelGGL(k_aggs, dim3(4 * AGG_NB), dim3(256), 0, stream, bufH, bufB, csr_src, row_start, dinv);
    hipLaunchKernelGGL(k_gemm2, dim3(NGEMM), dim3(256), 0, stream, bufB, Wct, bmu, bls, out);
}

// Round 5
// 444.881 us; speedup vs baseline: 1.0243x; 1.0243x over previous
//
#include <hip/hip_runtime.h>
#include <hip/hip_fp16.h>

#define N_NODES 100000
#define HALF_N  50000
#define IN_CH 128
#define OUT_CH 64
#define HID 128
#define N_EDGES 1600000

#define NBUCK 196               // dst >> 9, max 99999>>9 = 195
#define BBLK  512               // binning blocks (2 per CU)
#define CHUNK (N_EDGES / BBLK)  // 3125 edges per binning block
#define NH    (NBUCK * BBLK)    // 100352 histogram entries

// slice-major fp16 feature layout: [4 slices][N_NODES][32 ch] -> 64-B rows = 1 line per gather.
// Edge lists per node are split by src-half (src < 50000). blockIdx&7 = (slice | half<<2)
// maps to the 8 XCDs round-robin: each XCD's gather working set = 32ch x 50k = 3.2 MB,
// RESIDENT in its 4 MB L2 (R2-proven regime) while total line requests = E x 4 = 6.4 M
// (half of R2/R3's 12.8 M). Two fp16 partial buffers combined in the GEMM A-load.
#define SLICE ((size_t)N_NODES * 32)   // halfs per slice
#define AGG_NB 1563                    // ceil(N / 64) node-blocks per (slice,half)

typedef _Float16 half8 __attribute__((ext_vector_type(8)));
typedef float floatx4 __attribute__((ext_vector_type(4)));

// ---------------- pass 1: per-(bucket,block) histogram (LDS atomics; fully overwrites hist) ----

__global__ __launch_bounds__(256) void k_hist(const int* __restrict__ dst, int* __restrict__ hist) {
    __shared__ int lh[NBUCK];
    int t = threadIdx.x;
    int blk = blockIdx.x;
    if (t < NBUCK) lh[t] = 0;
    __syncthreads();
    int base = blk * CHUNK;
    for (int i = base + t; i < base + CHUNK; i += 256) {
        atomicAdd(&lh[dst[i] >> 9], 1);
    }
    __syncthreads();
    if (t < NBUCK) hist[t * BBLK + blk] = lh[t];
}

// ---------------- hierarchical exclusive scan (hist only) ----------------

#define SCAN_T 1024
__global__ void k_scan_local(const int* __restrict__ in, int* __restrict__ excl,
                             int* __restrict__ bsum, int n) {
    __shared__ int tmp[SCAN_T];
    int t = threadIdx.x;
    int i = blockIdx.x * SCAN_T + t;
    int v = (i < n) ? in[i] : 0;
    tmp[t] = v;
    __syncthreads();
    for (int off = 1; off < SCAN_T; off <<= 1) {
        int u = (t >= off) ? tmp[t - off] : 0;
        __syncthreads();
        tmp[t] += u;
        __syncthreads();
    }
    if (i < n) excl[i] = tmp[t] - v;
    if (t == SCAN_T - 1) bsum[blockIdx.x] = tmp[t];
}

__global__ void k_scan_sums(const int* __restrict__ bsum, int* __restrict__ boff, int nb) {
    __shared__ int tmp[128];
    int t = threadIdx.x;
    int v = (t < nb) ? bsum[t] : 0;
    tmp[t] = v;
    __syncthreads();
    for (int off = 1; off < 128; off <<= 1) {
        int u = (t >= off) ? tmp[t - off] : 0;
        __syncthreads();
        tmp[t] += u;
        __syncthreads();
    }
    if (t < nb) boff[t] = tmp[t] - v;
}

__global__ void k_scan_add1(const int* __restrict__ excl, const int* __restrict__ boff,
                            int* __restrict__ out, int n) {
    int i = blockIdx.x * blockDim.x + threadIdx.x;
    if (i < n) out[i] = excl[i] + boff[i / SCAN_T];
}

// ---------------- pass 2: scatter edges into bucket-partitioned array ----------------

__global__ __launch_bounds__(256) void k_binscatter(const int* __restrict__ src,
                                                    const int* __restrict__ dst,
                                                    const int* __restrict__ off,
                                                    int2* __restrict__ binned) {
    __shared__ int loff[NBUCK];
    int t = threadIdx.x;
    int blk = blockIdx.x;
    if (t < NBUCK) loff[t] = off[t * BBLK + blk];
    __syncthreads();
    int base = blk * CHUNK;
    for (int i = base + t; i < base + CHUNK; i += 256) {
        int d = dst[i];
        int s = src[i];
        int pos = atomicAdd(&loff[d >> 9], 1);
        binned[pos] = make_int2(s, d);
    }
}

// ---------------- pass 3: per-bucket degree/scan/fill, now with src-half split ----------------
// Produces row_start (with sentinel), split (src-half boundary per row), dinv, csr_src.

__global__ __launch_bounds__(256) void k_bucket(const int2* __restrict__ binned,
                                                const int* __restrict__ off,
                                                int* __restrict__ row_start,
                                                int* __restrict__ split,
                                                float* __restrict__ dinv,
                                                int* __restrict__ csr_src) {
    __shared__ int cnt[1024];   // (node&511)*2 + (src>=HALF_N)
    __shared__ int ps[256];
    __shared__ int cur[1024];
    int b = blockIdx.x;
    int t = threadIdx.x;
    int start = off[b * BBLK];
    int end = (b + 1 < NBUCK) ? off[(b + 1) * BBLK] : N_EDGES;
    cnt[t] = 0;
    cnt[t + 256] = 0;
    cnt[t + 512] = 0;
    cnt[t + 768] = 0;
    if (b == NBUCK - 1 && t == 0) row_start[N_NODES] = N_EDGES;  // sentinel
    __syncthreads();
    for (int i = start + t; i < end; i += 256) {
        int2 e = binned[i];
        atomicAdd(&cnt[((e.y & 511) << 1) | (e.x >= HALF_N)], 1);
    }
    __syncthreads();
    int c00 = cnt[4 * t], c01 = cnt[4 * t + 1];   // node 2t: half0, half1
    int c10 = cnt[4 * t + 2], c11 = cnt[4 * t + 3]; // node 2t+1
    ps[t] = c00 + c01 + c10 + c11;
    __syncthreads();
    for (int o = 1; o < 256; o <<= 1) {
        int u = (t >= o) ? ps[t - o] : 0;
        __syncthreads();
        ps[t] += u;
        __syncthreads();
    }
    int pe = ps[t] - (c00 + c01 + c10 + c11);
    int e0 = start + pe;        // node 2t row begin
    int s0 = e0 + c00;          // node 2t half-split
    int e1 = s0 + c01;          // node 2t+1 row begin
    int s1 = e1 + c10;          // node 2t+1 half-split
    cur[4 * t] = e0;
    cur[4 * t + 1] = s0;
    cur[4 * t + 2] = e1;
    cur[4 * t + 3] = s1;
    int node0 = (b << 9) + 2 * t;
    if (node0 < N_NODES) {
        row_start[node0] = e0;
        split[node0] = s0;
        dinv[node0] = rsqrtf((float)(c00 + c01 + 1));
    }
    if (node0 + 1 < N_NODES) {
        row_start[node0 + 1] = e1;
        split[node0 + 1] = s1;
        dinv[node0 + 1] = rsqrtf((float)(c10 + c11 + 1));
    }
    __syncthreads();
    for (int i = start + t; i < end; i += 256) {
        int2 e = binned[i];
        int p = atomicAdd(&cur[((e.y & 511) << 1) | (e.x >= HALF_N)], 1);
        csr_src[p] = e.x;
    }
}

// ---------------- cast + pre-scale into SLICE-MAJOR [4][N][32] layout, + folded weight prep ----

__global__ __launch_bounds__(256) void k_cast_prep(const float* __restrict__ in,
                                                   const float* __restrict__ dinv,
                                                   __half* __restrict__ out,
                                                   const float* __restrict__ W1,
                                                   const float* __restrict__ Wmu,
                                                   const float* __restrict__ Wls,
                                                   __half* __restrict__ W1t,
                                                   __half* __restrict__ Wct) {
    int blk = blockIdx.x;
    int t = threadIdx.x;
    if (blk >= 12500) {  // weight prep tail blocks (64 blocks x 256 = 16384)
        int i = (blk - 12500) * 256 + t;
        if (i < 128 * 128) {
            int n = i >> 7, k = i & 127;
            W1t[i] = __float2half(W1[k * 128 + n]);
            Wct[i] = __float2half(n < 64 ? Wmu[k * 64 + n] : Wls[k * 64 + (n - 64)]);
        }
        return;
    }
    int i = blk * 256 + t;  // over float4 groups, 32 per row; 12500*256 = N_NODES*32 exact
    float4 v = ((const float4*)in)[i];
    int node = i >> 5, ch4 = i & 31;
    float d = dinv[node];
    size_t o = (size_t)(ch4 >> 3) * (SLICE / 2) + (size_t)node * 16 + (size_t)(ch4 & 7) * 2;
    ((__half2*)out)[o]     = __floats2half2_rn(d * v.x, d * v.y);
    ((__half2*)out)[o + 1] = __floats2half2_rn(d * v.z, d * v.w);
}

// ---------------- aggregation: XCD-resident (slice, src-half) partials ----------------
// combo = blockIdx&7 = slice | (half<<2) -> XCD pinning. Each block gathers only srcs in its
// half -> per-XCD working set 3.2 MB (L2-resident). Partial (pre-scaled by dinv[dst], self in
// half 0) written fp16 non-temporally. Wave = 16 node-groups x 4 lanes x half8 (16 B = 1/4 line;
// a group's 4 lanes cover exactly one 64-B line). Unroll-4 -> 64 lines in flight per wave.

__global__ __launch_bounds__(256) void k_aggs(const __half* __restrict__ in,
                                              __half* __restrict__ out0,
                                              __half* __restrict__ out1,
                                              const int* __restrict__ csr_src,
                                              const int* __restrict__ row_start,
                                              const int* __restrict__ split,
                                              const float* __restrict__ dinv) {
    int combo = blockIdx.x & 7;
    int slice = combo & 3;
    int half = combo >> 2;
    int nb = blockIdx.x >> 3;                 // 0..AGG_NB-1
    const __half* ins = in + (size_t)slice * SLICE;
    __half* outs = (half ? out1 : out0) + (size_t)slice * SLICE;
    int t = threadIdx.x;
    int lane = t & 63;
    int g = lane >> 2;                        // node sub-group 0..15
    int ch8 = (lane & 3) * 8;                 // half offset within 32-ch row
    int w = nb * 64 + (t >> 6) * 16 + g;
    if (w >= N_NODES) return;
    int beg, endv;
    if (half == 0) { beg = row_start[w]; endv = split[w]; }
    else           { beg = split[w];     endv = row_start[w + 1]; }
    int cnt = endv - beg;
    float di = dinv[w];
    const int* __restrict__ cp = csr_src + beg;
    float a0 = 0.f, a1 = 0.f, a2 = 0.f, a3 = 0.f, a4 = 0.f, a5 = 0.f, a6 = 0.f, a7 = 0.f;
    if (half == 0) {  // self term lives in half 0's partial
        half8 sv = *(const half8*)(ins + (size_t)w * 32 + ch8);
        a0 = (float)sv[0]; a1 = (float)sv[1]; a2 = (float)sv[2]; a3 = (float)sv[3];
        a4 = (float)sv[4]; a5 = (float)sv[5]; a6 = (float)sv[6]; a7 = (float)sv[7];
    }
    int j = 0;
    for (; j + 3 < cnt; j += 4) {
        int s0 = __builtin_nontemporal_load(cp + j);
        int s1 = __builtin_nontemporal_load(cp + j + 1);
        int s2 = __builtin_nontemporal_load(cp + j + 2);
        int s3 = __builtin_nontemporal_load(cp + j + 3);
        half8 v0 = *(const half8*)(ins + (size_t)s0 * 32 + ch8);
        half8 v1 = *(const half8*)(ins + (size_t)s1 * 32 + ch8);
        half8 v2 = *(const half8*)(ins + (size_t)s2 * 32 + ch8);
        half8 v3 = *(const half8*)(ins + (size_t)s3 * 32 + ch8);
        a0 += (float)v0[0] + (float)v1[0] + (float)v2[0] + (float)v3[0];
        a1 += (float)v0[1] + (float)v1[1] + (float)v2[1] + (float)v3[1];
        a2 += (float)v0[2] + (float)v1[2] + (float)v2[2] + (float)v3[2];
        a3 += (float)v0[3] + (float)v1[3] + (float)v2[3] + (float)v3[3];
        a4 += (float)v0[4] + (float)v1[4] + (float)v2[4] + (float)v3[4];
        a5 += (float)v0[5] + (float)v1[5] + (float)v2[5] + (float)v3[5];
        a6 += (float)v0[6] + (float)v1[6] + (float)v2[6] + (float)v3[6];
        a7 += (float)v0[7] + (float)v1[7] + (float)v2[7] + (float)v3[7];
    }
    for (; j < cnt; j++) {
        int s0 = __builtin_nontemporal_load(cp + j);
        half8 v0 = *(const half8*)(ins + (size_t)s0 * 32 + ch8);
        a0 += (float)v0[0];
        a1 += (float)v0[1];
        a2 += (float)v0[2];
        a3 += (float)v0[3];
        a4 += (float)v0[4];
        a5 += (float)v0[5];
        a6 += (float)v0[6];
        a7 += (float)v0[7];
    }
    half8 o;
    o[0] = (_Float16)(di * a0);
    o[1] = (_Float16)(di * a1);
    o[2] = (_Float16)(di * a2);
    o[3] = (_Float16)(di * a3);
    o[4] = (_Float16)(di * a4);
    o[5] = (_Float16)(di * a5);
    o[6] = (_Float16)(di * a6);
    o[7] = (_Float16)(di * a7);
    __builtin_nontemporal_store(o, (half8*)(outs + (size_t)w * 32 + ch8));
}

// ---------------- GEMM1 (MFMA): H = dinv * relu_normalize(relu((A0+A1) @ W1 + b1)) ------------
// A0/A1 slice-major [4][N][32] fp16 partials; summed per fragment (1 v_pk_add_f16 per 2 ch).

__global__ __launch_bounds__(256) void k_gemm1(const __half* __restrict__ A0,
                                               const __half* __restrict__ A1,
                                               const __half* __restrict__ Wt,
                                               const float* __restrict__ b,
                                               const float* __restrict__ dinv,
                                               __half* __restrict__ H) {
    int t = threadIdx.x;
    int wv = t >> 6;
    int lane = t & 63;
    int m16 = lane & 15;
    int quad = lane >> 4;
    int row = blockIdx.x * 64 + wv * 16 + m16;
    floatx4 acc[8];
    #pragma unroll
    for (int tt = 0; tt < 8; tt++) acc[tt] = (floatx4){0.f, 0.f, 0.f, 0.f};
    #pragma unroll
    for (int kk = 0; kk < 4; kk++) {
        size_t aoff = (size_t)kk * SLICE + (size_t)row * 32 + quad * 8;
        half8 a = *(const half8*)(A0 + aoff) + *(const half8*)(A1 + aoff);
        #pragma unroll
        for (int tt = 0; tt < 8; tt++) {
            half8 bf = *(const half8*)(Wt + (size_t)(tt * 16 + m16) * 128 + kk * 32 + quad * 8);
            acc[tt] = __builtin_amdgcn_mfma_f32_16x16x32_f16(a, bf, acc[tt], 0, 0, 0);
        }
    }
    float bias[8];
    #pragma unroll
    for (int tt = 0; tt < 8; tt++) bias[tt] = b[tt * 16 + m16];
    int rbase = blockIdx.x * 64 + wv * 16 + quad * 4;
    #pragma unroll
    for (int r = 0; r < 4; r++) {
        int rw = rbase + r;
        float vv[8];
        float ssq = 0.f;
        #pragma unroll
        for (int tt = 0; tt < 8; tt++) {
            float v = fmaxf(acc[tt][r] + bias[tt], 0.f);
            vv[tt] = v;
            ssq += v * v;
        }
        ssq += __shfl_xor(ssq, 1, 64);
        ssq += __shfl_xor(ssq, 2, 64);
        ssq += __shfl_xor(ssq, 4, 64);
        ssq += __shfl_xor(ssq, 8, 64);
        float s = 1.0f / fmaxf(sqrtf(ssq), 1e-12f);
        if (rw < N_NODES) {
            float sc = s * dinv[rw];  // pre-scale for the next aggregation
            #pragma unroll
            for (int tt = 0; tt < 8; tt++) {
                H[(size_t)(tt >> 1) * SLICE + (size_t)rw * 32 + (tt & 1) * 16 + m16] =
                    __float2half(vv[tt] * sc);
            }
        }
    }
}

// ---------------- GEMM2 (MFMA): out = [ (B0+B1)@Wmu+bmu | (B0+B1)@Wls+bls ] ----------------

__global__ __launch_bounds__(256) void k_gemm2(const __half* __restrict__ A0,
                                               const __half* __restrict__ A1,
                                               const __half* __restrict__ Wt,
                                               const float* __restrict__ bmu,
                                               const float* __restrict__ bls,
                                               float* __restrict__ out) {
    int t = threadIdx.x;
    int wv = t >> 6;
    int lane = t & 63;
    int m16 = lane & 15;
    int quad = lane >> 4;
    int row = blockIdx.x * 64 + wv * 16 + m16;
    floatx4 acc[8];
    #pragma unroll
    for (int tt = 0; tt < 8; tt++) acc[tt] = (floatx4){0.f, 0.f, 0.f, 0.f};
    #pragma unroll
    for (int kk = 0; kk < 4; kk++) {
        size_t aoff = (size_t)kk * SLICE + (size_t)row * 32 + quad * 8;
        half8 a = *(const half8*)(A0 + aoff) + *(const half8*)(A1 + aoff);
        #pragma unroll
        for (int tt = 0; tt < 8; tt++) {
            half8 bf = *(const half8*)(Wt + (size_t)(tt * 16 + m16) * 128 + kk * 32 + quad * 8);
            acc[tt] = __builtin_amdgcn_mfma_f32_16x16x32_f16(a, bf, acc[tt], 0, 0, 0);
        }
    }
    float bias[8];
    #pragma unroll
    for (int tt = 0; tt < 8; tt++)
        bias[tt] = (tt < 4) ? bmu[tt * 16 + m16] : bls[(tt - 4) * 16 + m16];
    int rbase = blockIdx.x * 64 + wv * 16 + quad * 4;
    #pragma unroll
    for (int r = 0; r < 4; r++) {
        int rw = rbase + r;
        if (rw < N_NODES) {
            #pragma unroll
            for (int tt = 0; tt < 4; tt++)
                out[(size_t)rw * 64 + tt * 16 + m16] = acc[tt][r] + bias[tt];
            #pragma unroll
            for (int tt = 4; tt < 8; tt++)
                out[(size_t)N_NODES * 64 + (size_t)rw * 64 + (tt - 4) * 16 + m16] = acc[tt][r] + bias[tt];
        }
    }
}

// ---------------- launch ----------------

extern "C" void kernel_launch(void* const* d_in, const int* in_sizes, int n_in,
                              void* d_out, int out_size, void* d_ws, size_t ws_size,
                              hipStream_t stream) {
    const float* x   = (const float*)d_in[0];
    const int*  eidx = (const int*)d_in[1];
    const float* W1  = (const float*)d_in[2];
    const float* b1  = (const float*)d_in[3];
    const float* Wmu = (const float*)d_in[4];
    const float* bmu = (const float*)d_in[5];
    const float* Wls = (const float*)d_in[6];
    const float* bls = (const float*)d_in[7];
    float* out = (float*)d_out;
    const int* e_src = eidx;
    const int* e_dst = eidx + N_EDGES;

    char* ws = (char*)d_ws;
    size_t off_b = 0;
    auto alloc = [&](size_t n) -> void* {
        void* p = ws + off_b;
        off_b += (n + 255) & ~(size_t)255;
        return p;
    };
    float*  dinv      = (float*)alloc((size_t)N_NODES * sizeof(float));
    int*    row_start = (int*)alloc((size_t)(N_NODES + 1) * sizeof(int));
    int*    split     = (int*)alloc((size_t)N_NODES * sizeof(int));
    int*    hist      = (int*)alloc((size_t)NH * sizeof(int));
    int*    excl2     = (int*)alloc((size_t)NH * sizeof(int));
    int*    bsum2     = (int*)alloc(1024 * sizeof(int));
    int*    boff2     = (int*)alloc(1024 * sizeof(int));
    int*    offs      = (int*)alloc((size_t)NH * sizeof(int));
    int*    csr_src   = (int*)alloc((size_t)N_EDGES * sizeof(int));
    int2*   binned    = (int2*)alloc((size_t)N_EDGES * sizeof(int2));
    __half* W1t       = (__half*)alloc((size_t)128 * 128 * sizeof(__half));
    __half* Wct       = (__half*)alloc((size_t)128 * 128 * sizeof(__half));
    __half* xs        = (__half*)alloc((size_t)N_NODES * IN_CH * sizeof(__half));
    __half* bufA0     = (__half*)alloc((size_t)N_NODES * HID * sizeof(__half));    // y1 partial h0
    __half* bufA1     = (__half*)alloc((size_t)N_NODES * HID * sizeof(__half));    // y1 partial h1
    __half* bufH      = (__half*)alloc((size_t)N_NODES * HID * sizeof(__half));    // hs = dinv*h
    alloc(32 * 1024);  // pad for OOB tile reads in last GEMM block
    // agg2 partials reuse bufA0/bufA1 (dead after gemm1); xs dead after agg1.
    __half* bufB0 = bufA0;
    __half* bufB1 = bufA1;

    const int NB_SCAN2 = (NH + SCAN_T - 1) / SCAN_T;  // 98
    const int NGEMM = (N_NODES + 63) / 64;            // 1563

    // CSR build: hist -> scan -> binscatter -> bucket (row_start, split, dinv, csr_src)
    hipLaunchKernelGGL(k_hist, dim3(BBLK), dim3(256), 0, stream, e_dst, hist);
    hipLaunchKernelGGL(k_scan_local, dim3(NB_SCAN2), dim3(SCAN_T), 0, stream, hist, excl2, bsum2, NH);
    hipLaunchKernelGGL(k_scan_sums, dim3(1), dim3(128), 0, stream, bsum2, boff2, NB_SCAN2);
    hipLaunchKernelGGL(k_scan_add1, dim3((NH + 255) / 256), dim3(256), 0, stream, excl2, boff2, offs, NH);
    hipLaunchKernelGGL(k_binscatter, dim3(BBLK), dim3(256), 0, stream, e_src, e_dst, offs, binned);
    hipLaunchKernelGGL(k_bucket, dim3(NBUCK), dim3(256), 0, stream, binned, offs, row_start, split, dinv, csr_src);
    // xs = fp16(dinv * x) slice-major, + folded weight prep (needs dinv)
    hipLaunchKernelGGL(k_cast_prep, dim3(12500 + 64), dim3(256), 0, stream, x, dinv, xs,
                       W1, Wmu, Wls, W1t, Wct);
    // layer 1
    hipLaunchKernelGGL(k_aggs, dim3(8 * AGG_NB), dim3(256), 0, stream, xs, bufA0, bufA1,
                       csr_src, row_start, split, dinv);
    hipLaunchKernelGGL(k_gemm1, dim3(NGEMM), dim3(256), 0, stream, bufA0, bufA1, W1t, b1, dinv, bufH);
    // shared aggregation for layers 2+3
    hipLaunchKernelGGL(k_aggs, dim3(8 * AGG_NB), dim3(256), 0, stream, bufH, bufB0, bufB1,
                       csr_src, row_start, split, dinv);
    hipLaunchKernelGGL(k_gemm2, dim3(NGEMM), dim3(256), 0, stream, bufB0, bufB1, Wct, bmu, bls, out);
}

// Round 6
// 402.268 us; speedup vs baseline: 1.1328x; 1.1059x over previous
//
#include <hip/hip_runtime.h>
#include <hip/hip_fp16.h>

#define N_NODES 100000
#define HALF_N  50000
#define IN_CH 128
#define OUT_CH 64
#define HID 128
#define N_EDGES 1600000

#define NBUCK 196               // dst >> 9, max 99999>>9 = 195
#define BBLK  512               // binning blocks (2 per CU)
#define CHUNK (N_EDGES / BBLK)  // 3125 edges per binning block
#define NH    (NBUCK * BBLK)    // 100352 histogram entries

// agg1: slice-major fp16 [4 slices][N][32 ch] (64-B rows, 1 line/gather), src-half split,
//       partial stores via inline-asm `sc1 nt` (write-through, no L2 allocate) to keep the
//       3.2 MB per-XCD gather table resident.  combo = blockIdx&7 = slice | half<<2 -> XCD pin.
// agg2: round-0 proven design (row-major [N][128], one wave/node, unroll-8) as in-bench A/B.
#define SLICE ((size_t)N_NODES * 32)   // halfs per slice
#define AGG_NB 1563                    // ceil(N/64) node-blocks per (slice,half)

typedef _Float16 half8 __attribute__((ext_vector_type(8)));
typedef float floatx4 __attribute__((ext_vector_type(4)));

// ---------------- pass 1: per-(bucket,block) histogram ----------------

__global__ __launch_bounds__(256) void k_hist(const int* __restrict__ dst, int* __restrict__ hist) {
    __shared__ int lh[NBUCK];
    int t = threadIdx.x;
    int blk = blockIdx.x;
    if (t < NBUCK) lh[t] = 0;
    __syncthreads();
    int base = blk * CHUNK;
    for (int i = base + t; i < base + CHUNK; i += 256) {
        atomicAdd(&lh[dst[i] >> 9], 1);
    }
    __syncthreads();
    if (t < NBUCK) hist[t * BBLK + blk] = lh[t];
}

// ---------------- hierarchical exclusive scan (local + sums; add folded into consumers) ------

#define SCAN_T 1024
__global__ void k_scan_local(const int* __restrict__ in, int* __restrict__ excl,
                             int* __restrict__ bsum, int n) {
    __shared__ int tmp[SCAN_T];
    int t = threadIdx.x;
    int i = blockIdx.x * SCAN_T + t;
    int v = (i < n) ? in[i] : 0;
    tmp[t] = v;
    __syncthreads();
    for (int off = 1; off < SCAN_T; off <<= 1) {
        int u = (t >= off) ? tmp[t - off] : 0;
        __syncthreads();
        tmp[t] += u;
        __syncthreads();
    }
    if (i < n) excl[i] = tmp[t] - v;
    if (t == SCAN_T - 1) bsum[blockIdx.x] = tmp[t];
}

__global__ void k_scan_sums(const int* __restrict__ bsum, int* __restrict__ boff, int nb) {
    __shared__ int tmp[128];
    int t = threadIdx.x;
    int v = (t < nb) ? bsum[t] : 0;
    tmp[t] = v;
    __syncthreads();
    for (int off = 1; off < 128; off <<= 1) {
        int u = (t >= off) ? tmp[t - off] : 0;
        __syncthreads();
        tmp[t] += u;
        __syncthreads();
    }
    if (t < nb) boff[t] = tmp[t] - v;
}

__device__ __forceinline__ int off_at(const int* excl, const int* boff, int i) {
    return excl[i] + boff[i >> 10];  // SCAN_T = 1024
}

// ---------------- pass 2: scatter edges into bucket-partitioned array ----------------

__global__ __launch_bounds__(256) void k_binscatter(const int* __restrict__ src,
                                                    const int* __restrict__ dst,
                                                    const int* __restrict__ excl,
                                                    const int* __restrict__ boff,
                                                    int2* __restrict__ binned) {
    __shared__ int loff[NBUCK];
    int t = threadIdx.x;
    int blk = blockIdx.x;
    if (t < NBUCK) loff[t] = off_at(excl, boff, t * BBLK + blk);
    __syncthreads();
    int base = blk * CHUNK;
    for (int i = base + t; i < base + CHUNK; i += 256) {
        int d = dst[i];
        int s = src[i];
        int pos = atomicAdd(&loff[d >> 9], 1);
        binned[pos] = make_int2(s, d);
    }
}

// ---------------- pass 3: per-bucket degree/scan/fill with src-half split ----------------

__global__ __launch_bounds__(256) void k_bucket(const int2* __restrict__ binned,
                                                const int* __restrict__ excl,
                                                const int* __restrict__ boff,
                                                int* __restrict__ row_start,
                                                int* __restrict__ split,
                                                float* __restrict__ dinv,
                                                int* __restrict__ csr_src) {
    __shared__ int cnt[1024];   // (node&511)*2 + (src>=HALF_N)
    __shared__ int ps[256];
    __shared__ int cur[1024];
    int b = blockIdx.x;
    int t = threadIdx.x;
    int start = off_at(excl, boff, b * BBLK);
    int end = (b + 1 < NBUCK) ? off_at(excl, boff, (b + 1) * BBLK) : N_EDGES;
    cnt[t] = 0;
    cnt[t + 256] = 0;
    cnt[t + 512] = 0;
    cnt[t + 768] = 0;
    if (b == NBUCK - 1 && t == 0) row_start[N_NODES] = N_EDGES;  // sentinel
    __syncthreads();
    for (int i = start + t; i < end; i += 256) {
        int2 e = binned[i];
        atomicAdd(&cnt[((e.y & 511) << 1) | (e.x >= HALF_N)], 1);
    }
    __syncthreads();
    int c00 = cnt[4 * t], c01 = cnt[4 * t + 1];
    int c10 = cnt[4 * t + 2], c11 = cnt[4 * t + 3];
    ps[t] = c00 + c01 + c10 + c11;
    __syncthreads();
    for (int o = 1; o < 256; o <<= 1) {
        int u = (t >= o) ? ps[t - o] : 0;
        __syncthreads();
        ps[t] += u;
        __syncthreads();
    }
    int pe = ps[t] - (c00 + c01 + c10 + c11);
    int e0 = start + pe;
    int s0 = e0 + c00;
    int e1 = s0 + c01;
    int s1 = e1 + c10;
    cur[4 * t] = e0;
    cur[4 * t + 1] = s0;
    cur[4 * t + 2] = e1;
    cur[4 * t + 3] = s1;
    int node0 = (b << 9) + 2 * t;
    if (node0 < N_NODES) {
        row_start[node0] = e0;
        split[node0] = s0;
        dinv[node0] = rsqrtf((float)(c00 + c01 + 1));
    }
    if (node0 + 1 < N_NODES) {
        row_start[node0 + 1] = e1;
        split[node0 + 1] = s1;
        dinv[node0 + 1] = rsqrtf((float)(c10 + c11 + 1));
    }
    __syncthreads();
    for (int i = start + t; i < end; i += 256) {
        int2 e = binned[i];
        int p = atomicAdd(&cur[((e.y & 511) << 1) | (e.x >= HALF_N)], 1);
        csr_src[p] = e.x;
    }
}

// ---------------- cast + pre-scale into [4][N][32] slice-major, + folded weight prep ----------

__global__ __launch_bounds__(256) void k_cast_prep(const float* __restrict__ in,
                                                   const float* __restrict__ dinv,
                                                   __half* __restrict__ out,
                                                   const float* __restrict__ W1,
                                                   const float* __restrict__ Wmu,
                                                   const float* __restrict__ Wls,
                                                   __half* __restrict__ W1t,
                                                   __half* __restrict__ Wct) {
    int blk = blockIdx.x;
    int t = threadIdx.x;
    if (blk >= 12500) {  // weight prep tail blocks
        int i = (blk - 12500) * 256 + t;
        if (i < 128 * 128) {
            int n = i >> 7, k = i & 127;
            W1t[i] = __float2half(W1[k * 128 + n]);
            Wct[i] = __float2half(n < 64 ? Wmu[k * 64 + n] : Wls[k * 64 + (n - 64)]);
        }
        return;
    }
    int i = blk * 256 + t;
    float4 v = ((const float4*)in)[i];
    int node = i >> 5, ch4 = i & 31;
    float d = dinv[node];
    size_t o = (size_t)(ch4 >> 3) * (SLICE / 2) + (size_t)node * 16 + (size_t)(ch4 & 7) * 2;
    ((__half2*)out)[o]     = __floats2half2_rn(d * v.x, d * v.y);
    ((__half2*)out)[o + 1] = __floats2half2_rn(d * v.z, d * v.w);
}

// ---------------- agg variant A (layer 1): XCD-resident slices + sc1 no-allocate stores -------
// combo = blockIdx&7 = slice | half<<2. Per-XCD read set = 3.2 MB (resident if stores bypass).
// Partial stores: inline-asm global_store_dwordx4 with `sc1 nt` -> write-through, no L2 alloc.
// csr + metadata loads NT so only the gather table occupies L2.

__global__ __launch_bounds__(256) void k_aggs(const __half* __restrict__ in,
                                              __half* __restrict__ out0,
                                              __half* __restrict__ out1,
                                              const int* __restrict__ csr_src,
                                              const int* __restrict__ row_start,
                                              const int* __restrict__ split,
                                              const float* __restrict__ dinv) {
    int combo = blockIdx.x & 7;
    int slice = combo & 3;
    int half = combo >> 2;
    int nb = blockIdx.x >> 3;
    const __half* ins = in + (size_t)slice * SLICE;
    __half* outs = (half ? out1 : out0) + (size_t)slice * SLICE;
    int t = threadIdx.x;
    int lane = t & 63;
    int g = lane >> 2;                        // node sub-group 0..15
    int ch8 = (lane & 3) * 8;                 // half offset within 32-ch row
    int w = nb * 64 + (t >> 6) * 16 + g;
    if (w >= N_NODES) return;
    int beg, endv;
    if (half == 0) { beg = __builtin_nontemporal_load(row_start + w);
                     endv = __builtin_nontemporal_load(split + w); }
    else           { beg = __builtin_nontemporal_load(split + w);
                     endv = __builtin_nontemporal_load(row_start + w + 1); }
    int cnt = endv - beg;
    float di = __builtin_nontemporal_load(dinv + w);
    const int* __restrict__ cp = csr_src + beg;
    float a0 = 0.f, a1 = 0.f, a2 = 0.f, a3 = 0.f, a4 = 0.f, a5 = 0.f, a6 = 0.f, a7 = 0.f;
    if (half == 0) {  // self term lives in half 0's partial
        half8 sv = *(const half8*)(ins + (size_t)w * 32 + ch8);
        a0 = (float)sv[0]; a1 = (float)sv[1]; a2 = (float)sv[2]; a3 = (float)sv[3];
        a4 = (float)sv[4]; a5 = (float)sv[5]; a6 = (float)sv[6]; a7 = (float)sv[7];
    }
    int j = 0;
    for (; j + 3 < cnt; j += 4) {
        int s0 = __builtin_nontemporal_load(cp + j);
        int s1 = __builtin_nontemporal_load(cp + j + 1);
        int s2 = __builtin_nontemporal_load(cp + j + 2);
        int s3 = __builtin_nontemporal_load(cp + j + 3);
        half8 v0 = *(const half8*)(ins + (size_t)s0 * 32 + ch8);
        half8 v1 = *(const half8*)(ins + (size_t)s1 * 32 + ch8);
        half8 v2 = *(const half8*)(ins + (size_t)s2 * 32 + ch8);
        half8 v3 = *(const half8*)(ins + (size_t)s3 * 32 + ch8);
        a0 += (float)v0[0] + (float)v1[0] + (float)v2[0] + (float)v3[0];
        a1 += (float)v0[1] + (float)v1[1] + (float)v2[1] + (float)v3[1];
        a2 += (float)v0[2] + (float)v1[2] + (float)v2[2] + (float)v3[2];
        a3 += (float)v0[3] + (float)v1[3] + (float)v2[3] + (float)v3[3];
        a4 += (float)v0[4] + (float)v1[4] + (float)v2[4] + (float)v3[4];
        a5 += (float)v0[5] + (float)v1[5] + (float)v2[5] + (float)v3[5];
        a6 += (float)v0[6] + (float)v1[6] + (float)v2[6] + (float)v3[6];
        a7 += (float)v0[7] + (float)v1[7] + (float)v2[7] + (float)v3[7];
    }
    for (; j < cnt; j++) {
        int s0 = __builtin_nontemporal_load(cp + j);
        half8 v0 = *(const half8*)(ins + (size_t)s0 * 32 + ch8);
        a0 += (float)v0[0];
        a1 += (float)v0[1];
        a2 += (float)v0[2];
        a3 += (float)v0[3];
        a4 += (float)v0[4];
        a5 += (float)v0[5];
        a6 += (float)v0[6];
        a7 += (float)v0[7];
    }
    half8 o;
    o[0] = (_Float16)(di * a0);
    o[1] = (_Float16)(di * a1);
    o[2] = (_Float16)(di * a2);
    o[3] = (_Float16)(di * a3);
    o[4] = (_Float16)(di * a4);
    o[5] = (_Float16)(di * a5);
    o[6] = (_Float16)(di * a6);
    o[7] = (_Float16)(di * a7);
    __half* outp = outs + (size_t)w * 32 + ch8;
    // no-allocate write-through store: keep partial stream out of the XCD's L2
    asm volatile("global_store_dwordx4 %0, %1, off sc1 nt" :: "v"(outp), "v"(o) : "memory");
}

// ---------------- agg variant B (layers 2+3): round-0 proven row-major design ----------------
// in/out row-major [N][128] fp16 pre-scaled; one wave per node; lane = channel pair; unroll-8.

__global__ __launch_bounds__(256) void k_agg0(const __half* __restrict__ in, __half* __restrict__ out,
                                              const int* __restrict__ csr_src,
                                              const int* __restrict__ row_start,
                                              const float* __restrict__ dinv) {
    int w = (blockIdx.x * 256 + threadIdx.x) >> 6;
    int lane = threadIdx.x & 63;
    int beg = row_start[w];
    int cnt = row_start[w + 1] - beg;
    float di = dinv[w];
    float2 acc = __half22float2(((const __half2*)(in + (size_t)w * 128))[lane]);  // self term
    int j = 0;
    for (; j + 7 < cnt; j += 8) {
        int s0 = csr_src[beg + j];
        int s1 = csr_src[beg + j + 1];
        int s2 = csr_src[beg + j + 2];
        int s3 = csr_src[beg + j + 3];
        int s4 = csr_src[beg + j + 4];
        int s5 = csr_src[beg + j + 5];
        int s6 = csr_src[beg + j + 6];
        int s7 = csr_src[beg + j + 7];
        float2 v0 = __half22float2(((const __half2*)(in + (size_t)s0 * 128))[lane]);
        float2 v1 = __half22float2(((const __half2*)(in + (size_t)s1 * 128))[lane]);
        float2 v2 = __half22float2(((const __half2*)(in + (size_t)s2 * 128))[lane]);
        float2 v3 = __half22float2(((const __half2*)(in + (size_t)s3 * 128))[lane]);
        float2 v4 = __half22float2(((const __half2*)(in + (size_t)s4 * 128))[lane]);
        float2 v5 = __half22float2(((const __half2*)(in + (size_t)s5 * 128))[lane]);
        float2 v6 = __half22float2(((const __half2*)(in + (size_t)s6 * 128))[lane]);
        float2 v7 = __half22float2(((const __half2*)(in + (size_t)s7 * 128))[lane]);
        acc.x += v0.x + v1.x + v2.x + v3.x + v4.x + v5.x + v6.x + v7.x;
        acc.y += v0.y + v1.y + v2.y + v3.y + v4.y + v5.y + v6.y + v7.y;
    }
    for (; j + 3 < cnt; j += 4) {
        int s0 = csr_src[beg + j];
        int s1 = csr_src[beg + j + 1];
        int s2 = csr_src[beg + j + 2];
        int s3 = csr_src[beg + j + 3];
        float2 v0 = __half22float2(((const __half2*)(in + (size_t)s0 * 128))[lane]);
        float2 v1 = __half22float2(((const __half2*)(in + (size_t)s1 * 128))[lane]);
        float2 v2 = __half22float2(((const __half2*)(in + (size_t)s2 * 128))[lane]);
        float2 v3 = __half22float2(((const __half2*)(in + (size_t)s3 * 128))[lane]);
        acc.x += v0.x + v1.x + v2.x + v3.x;
        acc.y += v0.y + v1.y + v2.y + v3.y;
    }
    for (; j < cnt; j++) {
        int s0 = csr_src[beg + j];
        float2 v0 = __half22float2(((const __half2*)(in + (size_t)s0 * 128))[lane]);
        acc.x += v0.x;
        acc.y += v0.y;
    }
    ((__half2*)(out + (size_t)w * 128))[lane] = __floats2half2_rn(di * acc.x, di * acc.y);
}

// ---------------- GEMM1 (MFMA): H = dinv * relu_normalize(relu((A0+A1) @ W1 + b1)) ------------
// A0/A1 slice-major [4][N][32] partials; H written ROW-major [N][128] for k_agg0.

__global__ __launch_bounds__(256) void k_gemm1(const __half* __restrict__ A0,
                                               const __half* __restrict__ A1,
                                               const __half* __restrict__ Wt,
                                               const float* __restrict__ b,
                                               const float* __restrict__ dinv,
                                               __half* __restrict__ H) {
    int t = threadIdx.x;
    int wv = t >> 6;
    int lane = t & 63;
    int m16 = lane & 15;
    int quad = lane >> 4;
    int row = blockIdx.x * 64 + wv * 16 + m16;
    floatx4 acc[8];
    #pragma unroll
    for (int tt = 0; tt < 8; tt++) acc[tt] = (floatx4){0.f, 0.f, 0.f, 0.f};
    #pragma unroll
    for (int kk = 0; kk < 4; kk++) {
        size_t aoff = (size_t)kk * SLICE + (size_t)row * 32 + quad * 8;
        half8 a = *(const half8*)(A0 + aoff) + *(const half8*)(A1 + aoff);
        #pragma unroll
        for (int tt = 0; tt < 8; tt++) {
            half8 bf = *(const half8*)(Wt + (size_t)(tt * 16 + m16) * 128 + kk * 32 + quad * 8);
            acc[tt] = __builtin_amdgcn_mfma_f32_16x16x32_f16(a, bf, acc[tt], 0, 0, 0);
        }
    }
    float bias[8];
    #pragma unroll
    for (int tt = 0; tt < 8; tt++) bias[tt] = b[tt * 16 + m16];
    int rbase = blockIdx.x * 64 + wv * 16 + quad * 4;
    #pragma unroll
    for (int r = 0; r < 4; r++) {
        int rw = rbase + r;
        float vv[8];
        float ssq = 0.f;
        #pragma unroll
        for (int tt = 0; tt < 8; tt++) {
            float v = fmaxf(acc[tt][r] + bias[tt], 0.f);
            vv[tt] = v;
            ssq += v * v;
        }
        ssq += __shfl_xor(ssq, 1, 64);
        ssq += __shfl_xor(ssq, 2, 64);
        ssq += __shfl_xor(ssq, 4, 64);
        ssq += __shfl_xor(ssq, 8, 64);
        float s = 1.0f / fmaxf(sqrtf(ssq), 1e-12f);
        if (rw < N_NODES) {
            float sc = s * dinv[rw];  // pre-scale for the next aggregation
            #pragma unroll
            for (int tt = 0; tt < 8; tt++) {
                H[(size_t)rw * 128 + tt * 16 + m16] = __float2half(vv[tt] * sc);
            }
        }
    }
}

// ---------------- GEMM2 (MFMA): out = [ Y2@Wmu+bmu | Y2@Wls+bls ], A row-major [N][128] -------

__global__ __launch_bounds__(256) void k_gemm2(const __half* __restrict__ A,
                                               const __half* __restrict__ Wt,
                                               const float* __restrict__ bmu,
                                               const float* __restrict__ bls,
                                               float* __restrict__ out) {
    int t = threadIdx.x;
    int wv = t >> 6;
    int lane = t & 63;
    int m16 = lane & 15;
    int quad = lane >> 4;
    int row = blockIdx.x * 64 + wv * 16 + m16;
    floatx4 acc[8];
    #pragma unroll
    for (int tt = 0; tt < 8; tt++) acc[tt] = (floatx4){0.f, 0.f, 0.f, 0.f};
    #pragma unroll
    for (int kk = 0; kk < 4; kk++) {
        half8 a = *(const half8*)(A + (size_t)row * 128 + kk * 32 + quad * 8);
        #pragma unroll
        for (int tt = 0; tt < 8; tt++) {
            half8 bf = *(const half8*)(Wt + (size_t)(tt * 16 + m16) * 128 + kk * 32 + quad * 8);
            acc[tt] = __builtin_amdgcn_mfma_f32_16x16x32_f16(a, bf, acc[tt], 0, 0, 0);
        }
    }
    float bias[8];
    #pragma unroll
    for (int tt = 0; tt < 8; tt++)
        bias[tt] = (tt < 4) ? bmu[tt * 16 + m16] : bls[(tt - 4) * 16 + m16];
    int rbase = blockIdx.x * 64 + wv * 16 + quad * 4;
    #pragma unroll
    for (int r = 0; r < 4; r++) {
        int rw = rbase + r;
        if (rw < N_NODES) {
            #pragma unroll
            for (int tt = 0; tt < 4; tt++)
                out[(size_t)rw * 64 + tt * 16 + m16] = acc[tt][r] + bias[tt];
            #pragma unroll
            for (int tt = 4; tt < 8; tt++)
                out[(size_t)N_NODES * 64 + (size_t)rw * 64 + (tt - 4) * 16 + m16] = acc[tt][r] + bias[tt];
        }
    }
}

// ---------------- launch ----------------

extern "C" void kernel_launch(void* const* d_in, const int* in_sizes, int n_in,
                              void* d_out, int out_size, void* d_ws, size_t ws_size,
                              hipStream_t stream) {
    const float* x   = (const float*)d_in[0];
    const int*  eidx = (const int*)d_in[1];
    const float* W1  = (const float*)d_in[2];
    const float* b1  = (const float*)d_in[3];
    const float* Wmu = (const float*)d_in[4];
    const float* bmu = (const float*)d_in[5];
    const float* Wls = (const float*)d_in[6];
    const float* bls = (const float*)d_in[7];
    float* out = (float*)d_out;
    const int* e_src = eidx;
    const int* e_dst = eidx + N_EDGES;

    char* ws = (char*)d_ws;
    size_t off_b = 0;
    auto alloc = [&](size_t n) -> void* {
        void* p = ws + off_b;
        off_b += (n + 255) & ~(size_t)255;
        return p;
    };
    float*  dinv      = (float*)alloc((size_t)N_NODES * sizeof(float));
    int*    row_start = (int*)alloc((size_t)(N_NODES + 1) * sizeof(int));
    int*    split     = (int*)alloc((size_t)N_NODES * sizeof(int));
    int*    hist      = (int*)alloc((size_t)NH * sizeof(int));
    int*    excl2     = (int*)alloc((size_t)NH * sizeof(int));
    int*    bsum2     = (int*)alloc(1024 * sizeof(int));
    int*    boff2     = (int*)alloc(1024 * sizeof(int));
    int*    csr_src   = (int*)alloc((size_t)N_EDGES * sizeof(int));
    int2*   binned    = (int2*)alloc((size_t)N_EDGES * sizeof(int2));
    __half* W1t       = (__half*)alloc((size_t)128 * 128 * sizeof(__half));
    __half* Wct       = (__half*)alloc((size_t)128 * 128 * sizeof(__half));
    __half* xs        = (__half*)alloc((size_t)N_NODES * IN_CH * sizeof(__half));  // slice-major
    __half* bufA0     = (__half*)alloc((size_t)N_NODES * HID * sizeof(__half));    // partial h0
    __half* bufA1     = (__half*)alloc((size_t)N_NODES * HID * sizeof(__half));    // partial h1
    __half* bufH      = (__half*)alloc((size_t)N_NODES * HID * sizeof(__half));    // H row-major
    alloc(32 * 1024);  // pad for OOB tile reads in last GEMM block
    __half* bufB = xs;  // xs dead after aggs1; reuse row-major for y2

    const int NB_SCAN2 = (NH + SCAN_T - 1) / SCAN_T;  // 98
    const int NGEMM = (N_NODES + 63) / 64;            // 1563

    // CSR build: hist -> scan(local+sums) -> binscatter -> bucket
    hipLaunchKernelGGL(k_hist, dim3(BBLK), dim3(256), 0, stream, e_dst, hist);
    hipLaunchKernelGGL(k_scan_local, dim3(NB_SCAN2), dim3(SCAN_T), 0, stream, hist, excl2, bsum2, NH);
    hipLaunchKernelGGL(k_scan_sums, dim3(1), dim3(128), 0, stream, bsum2, boff2, NB_SCAN2);
    hipLaunchKernelGGL(k_binscatter, dim3(BBLK), dim3(256), 0, stream, e_src, e_dst, excl2, boff2, binned);
    hipLaunchKernelGGL(k_bucket, dim3(NBUCK), dim3(256), 0, stream, binned, excl2, boff2,
                       row_start, split, dinv, csr_src);
    // xs = fp16(dinv * x) slice-major, + folded weight prep
    hipLaunchKernelGGL(k_cast_prep, dim3(12500 + 64), dim3(256), 0, stream, x, dinv, xs,
                       W1, Wmu, Wls, W1t, Wct);
    // layer 1: sliced agg (A) + partial-combining GEMM -> H row-major
    hipLaunchKernelGGL(k_aggs, dim3(8 * AGG_NB), dim3(256), 0, stream, xs, bufA0, bufA1,
                       csr_src, row_start, split, dinv);
    hipLaunchKernelGGL(k_gemm1, dim3(NGEMM), dim3(256), 0, stream, bufA0, bufA1, W1t, b1, dinv, bufH);
    // layers 2+3: round-0 agg (B) + GEMM2
    hipLaunchKernelGGL(k_agg0, dim3(N_NODES / 4), dim3(256), 0, stream, bufH, bufB, csr_src, row_start, dinv);
    hipLaunchKernelGGL(k_gemm2, dim3(NGEMM), dim3(256), 0, stream, bufB, Wct, bmu, bls, out);
}

// Round 7
// 371.341 us; speedup vs baseline: 1.2272x; 1.0833x over previous
//
#include <hip/hip_runtime.h>
#include <hip/hip_fp16.h>

#define N_NODES 100000
#define IN_CH 128
#define OUT_CH 64
#define HID 128
#define N_EDGES 1600000

// CSR build: 782 buckets of 128 dst-nodes (dst>>7). 99999>>7 = 781.
#define NBUCK 782
#define BBLK  512               // binning blocks
#define CHUNK (N_EDGES / BBLK)  // 3125 edges per binning block

typedef _Float16 half8 __attribute__((ext_vector_type(8)));
typedef float floatx4 __attribute__((ext_vector_type(4)));

// ---------------- CSR pass 1: bucket totals (per-block LDS hist -> global atomicAdd) ----------

__global__ __launch_bounds__(256) void k_hist(const int* __restrict__ dst, int* __restrict__ btot) {
    __shared__ int lh[NBUCK];
    int t = threadIdx.x;
    int blk = blockIdx.x;
    for (int i = t; i < NBUCK; i += 256) lh[i] = 0;
    __syncthreads();
    int base = blk * CHUNK;
    for (int i = base + t; i < base + CHUNK; i += 256) {
        atomicAdd(&lh[dst[i] >> 7], 1);
    }
    __syncthreads();
    for (int i = t; i < NBUCK; i += 256) {
        int c = lh[i];
        if (c) atomicAdd(&btot[i], c);
    }
}

// ---------------- CSR pass 2: single-block scan of 782 bucket totals ----------------

__global__ __launch_bounds__(1024) void k_bases(const int* __restrict__ btot,
                                                int* __restrict__ bbase,
                                                int* __restrict__ bcur) {
    __shared__ int tmp[1024];
    int t = threadIdx.x;
    int v = (t < NBUCK) ? btot[t] : 0;
    tmp[t] = v;
    __syncthreads();
    for (int off = 1; off < 1024; off <<= 1) {
        int u = (t >= off) ? tmp[t - off] : 0;
        __syncthreads();
        tmp[t] += u;
        __syncthreads();
    }
    if (t < NBUCK) {
        int excl = tmp[t] - v;
        bbase[t] = excl;
        bcur[t] = excl;
    }
    if (t == NBUCK - 1) bbase[NBUCK] = tmp[t];  // = N_EDGES
}

// ---------------- CSR pass 3: scatter edges into bucket-contiguous array ----------------
// Per block: LDS-count its chunk -> reserve per-bucket ranges (1 atomic per (block,bucket))
// -> scatter. binned entry packs src (17 bits) | dst&127 (bits 17..23).

__global__ __launch_bounds__(256) void k_binscatter(const int* __restrict__ src,
                                                    const int* __restrict__ dst,
                                                    int* __restrict__ bcur,
                                                    int* __restrict__ binned) {
    __shared__ int cnt[NBUCK];
    __shared__ int base[NBUCK];
    int t = threadIdx.x;
    int blk = blockIdx.x;
    for (int i = t; i < NBUCK; i += 256) cnt[i] = 0;
    __syncthreads();
    int cbase = blk * CHUNK;
    for (int i = cbase + t; i < cbase + CHUNK; i += 256) {
        atomicAdd(&cnt[dst[i] >> 7], 1);
    }
    __syncthreads();
    for (int i = t; i < NBUCK; i += 256) {
        int c = cnt[i];
        if (c) base[i] = atomicAdd(&bcur[i], c);
        cnt[i] = 0;  // reuse as cursor
    }
    __syncthreads();
    for (int i = cbase + t; i < cbase + CHUNK; i += 256) {
        int d = dst[i];
        int s = src[i];
        int b = d >> 7;
        int pos = base[b] + atomicAdd(&cnt[b], 1);
        binned[pos] = s | ((d & 127) << 17);
    }
}

// ---------------- CSR pass 4: per-bucket degree/scan/fill (782 blocks, 128 nodes each) --------
// Produces row_start (with sentinel), dinv, csr_src.

__global__ __launch_bounds__(256) void k_bucket(const int* __restrict__ binned,
                                                const int* __restrict__ bbase,
                                                int* __restrict__ row_start,
                                                float* __restrict__ dinv,
                                                int* __restrict__ csr_src) {
    __shared__ int cnt[128];
    __shared__ int ps[128];
    __shared__ int cur[128];
    int b = blockIdx.x;
    int t = threadIdx.x;
    int start = bbase[b];
    int end = bbase[b + 1];
    if (t < 128) cnt[t] = 0;
    if (b == NBUCK - 1 && t == 0) row_start[N_NODES] = N_EDGES;  // sentinel
    __syncthreads();
    for (int i = start + t; i < end; i += 256) {
        atomicAdd(&cnt[(binned[i] >> 17) & 127], 1);
    }
    __syncthreads();
    int c = (t < 128) ? cnt[t] : 0;
    if (t < 128) ps[t] = c;
    __syncthreads();
    for (int o = 1; o < 128; o <<= 1) {
        int u = (t < 128 && t >= o) ? ps[t - o] : 0;
        __syncthreads();
        if (t < 128) ps[t] += u;
        __syncthreads();
    }
    if (t < 128) {
        int e = start + ps[t] - c;
        cur[t] = e;
        int node = (b << 7) + t;
        if (node < N_NODES) {
            row_start[node] = e;
            dinv[node] = rsqrtf((float)(c + 1));
        }
    }
    __syncthreads();
    for (int i = start + t; i < end; i += 256) {
        int v = binned[i];
        int p = atomicAdd(&cur[(v >> 17) & 127], 1);
        csr_src[p] = v & 0x1FFFF;
    }
}

// ---------------- cast + pre-scale (row-major [N][128]) + folded weight prep ----------------

__global__ __launch_bounds__(256) void k_cast_prep(const float* __restrict__ in,
                                                   const float* __restrict__ dinv,
                                                   __half* __restrict__ out,
                                                   const float* __restrict__ W1,
                                                   const float* __restrict__ Wmu,
                                                   const float* __restrict__ Wls,
                                                   __half* __restrict__ W1t,
                                                   __half* __restrict__ Wct) {
    int blk = blockIdx.x;
    int t = threadIdx.x;
    if (blk >= 12500) {  // weight prep tail blocks (64 x 256 = 16384)
        int i = (blk - 12500) * 256 + t;
        if (i < 128 * 128) {
            int n = i >> 7, k = i & 127;
            W1t[i] = __float2half(W1[k * 128 + n]);
            Wct[i] = __float2half(n < 64 ? Wmu[k * 64 + n] : Wls[k * 64 + (n - 64)]);
        }
        return;
    }
    int i = blk * 256 + t;  // float4 groups, 32 per row; 12500*256 = N*32 exact
    float4 v = ((const float4*)in)[i];
    float d = dinv[i >> 5];
    ((__half2*)out)[2 * i]     = __floats2half2_rn(d * v.x, d * v.y);
    ((__half2*)out)[2 * i + 1] = __floats2half2_rn(d * v.z, d * v.w);
}

// ---------------- aggregation (round-0 proven): y[w] = dinv[w]*(xs[w] + sum xs[src]) ---------
// row-major [N][128] fp16 pre-scaled; one wave per node; lane = channel pair; unroll-8.

__global__ __launch_bounds__(256) void k_agg(const __half* __restrict__ in, __half* __restrict__ out,
                                             const int* __restrict__ csr_src,
                                             const int* __restrict__ row_start,
                                             const float* __restrict__ dinv) {
    int w = (blockIdx.x * 256 + threadIdx.x) >> 6;
    int lane = threadIdx.x & 63;
    int beg = row_start[w];
    int cnt = row_start[w + 1] - beg;
    float di = dinv[w];
    float2 acc = __half22float2(((const __half2*)(in + (size_t)w * 128))[lane]);  // self term
    int j = 0;
    for (; j + 7 < cnt; j += 8) {
        int s0 = csr_src[beg + j];
        int s1 = csr_src[beg + j + 1];
        int s2 = csr_src[beg + j + 2];
        int s3 = csr_src[beg + j + 3];
        int s4 = csr_src[beg + j + 4];
        int s5 = csr_src[beg + j + 5];
        int s6 = csr_src[beg + j + 6];
        int s7 = csr_src[beg + j + 7];
        float2 v0 = __half22float2(((const __half2*)(in + (size_t)s0 * 128))[lane]);
        float2 v1 = __half22float2(((const __half2*)(in + (size_t)s1 * 128))[lane]);
        float2 v2 = __half22float2(((const __half2*)(in + (size_t)s2 * 128))[lane]);
        float2 v3 = __half22float2(((const __half2*)(in + (size_t)s3 * 128))[lane]);
        float2 v4 = __half22float2(((const __half2*)(in + (size_t)s4 * 128))[lane]);
        float2 v5 = __half22float2(((const __half2*)(in + (size_t)s5 * 128))[lane]);
        float2 v6 = __half22float2(((const __half2*)(in + (size_t)s6 * 128))[lane]);
        float2 v7 = __half22float2(((const __half2*)(in + (size_t)s7 * 128))[lane]);
        acc.x += v0.x + v1.x + v2.x + v3.x + v4.x + v5.x + v6.x + v7.x;
        acc.y += v0.y + v1.y + v2.y + v3.y + v4.y + v5.y + v6.y + v7.y;
    }
    for (; j + 3 < cnt; j += 4) {
        int s0 = csr_src[beg + j];
        int s1 = csr_src[beg + j + 1];
        int s2 = csr_src[beg + j + 2];
        int s3 = csr_src[beg + j + 3];
        float2 v0 = __half22float2(((const __half2*)(in + (size_t)s0 * 128))[lane]);
        float2 v1 = __half22float2(((const __half2*)(in + (size_t)s1 * 128))[lane]);
        float2 v2 = __half22float2(((const __half2*)(in + (size_t)s2 * 128))[lane]);
        float2 v3 = __half22float2(((const __half2*)(in + (size_t)s3 * 128))[lane]);
        acc.x += v0.x + v1.x + v2.x + v3.x;
        acc.y += v0.y + v1.y + v2.y + v3.y;
    }
    for (; j < cnt; j++) {
        int s0 = csr_src[beg + j];
        float2 v0 = __half22float2(((const __half2*)(in + (size_t)s0 * 128))[lane]);
        acc.x += v0.x;
        acc.y += v0.y;
    }
    ((__half2*)(out + (size_t)w * 128))[lane] = __floats2half2_rn(di * acc.x, di * acc.y);
}

// ---------------- GEMM1 (MFMA): H = dinv * relu_normalize(relu(A @ W1 + b1)) ----------------
// A row-major [N][128]; H row-major [N][128], pre-scaled by dinv for agg2.

__global__ __launch_bounds__(256) void k_gemm1(const __half* __restrict__ A,
                                               const __half* __restrict__ Wt,
                                               const float* __restrict__ b,
                                               const float* __restrict__ dinv,
                                               __half* __restrict__ H) {
    int t = threadIdx.x;
    int wv = t >> 6;
    int lane = t & 63;
    int m16 = lane & 15;
    int quad = lane >> 4;
    int row = blockIdx.x * 64 + wv * 16 + m16;
    floatx4 acc[8];
    #pragma unroll
    for (int tt = 0; tt < 8; tt++) acc[tt] = (floatx4){0.f, 0.f, 0.f, 0.f};
    #pragma unroll
    for (int kk = 0; kk < 4; kk++) {
        half8 a = *(const half8*)(A + (size_t)row * 128 + kk * 32 + quad * 8);
        #pragma unroll
        for (int tt = 0; tt < 8; tt++) {
            half8 bf = *(const half8*)(Wt + (size_t)(tt * 16 + m16) * 128 + kk * 32 + quad * 8);
            acc[tt] = __builtin_amdgcn_mfma_f32_16x16x32_f16(a, bf, acc[tt], 0, 0, 0);
        }
    }
    float bias[8];
    #pragma unroll
    for (int tt = 0; tt < 8; tt++) bias[tt] = b[tt * 16 + m16];
    int rbase = blockIdx.x * 64 + wv * 16 + quad * 4;
    #pragma unroll
    for (int r = 0; r < 4; r++) {
        int rw = rbase + r;
        float vv[8];
        float ssq = 0.f;
        #pragma unroll
        for (int tt = 0; tt < 8; tt++) {
            float v = fmaxf(acc[tt][r] + bias[tt], 0.f);
            vv[tt] = v;
            ssq += v * v;
        }
        ssq += __shfl_xor(ssq, 1, 64);
        ssq += __shfl_xor(ssq, 2, 64);
        ssq += __shfl_xor(ssq, 4, 64);
        ssq += __shfl_xor(ssq, 8, 64);
        float s = 1.0f / fmaxf(sqrtf(ssq), 1e-12f);
        if (rw < N_NODES) {
            float sc = s * dinv[rw];  // pre-scale for the next aggregation
            #pragma unroll
            for (int tt = 0; tt < 8; tt++) {
                H[(size_t)rw * 128 + tt * 16 + m16] = __float2half(vv[tt] * sc);
            }
        }
    }
}

// ---------------- GEMM2 (MFMA): out = [ Y2@Wmu+bmu | Y2@Wls+bls ] ----------------

__global__ __launch_bounds__(256) void k_gemm2(const __half* __restrict__ A,
                                               const __half* __restrict__ Wt,
                                               const float* __restrict__ bmu,
                                               const float* __restrict__ bls,
                                               float* __restrict__ out) {
    int t = threadIdx.x;
    int wv = t >> 6;
    int lane = t & 63;
    int m16 = lane & 15;
    int quad = lane >> 4;
    int row = blockIdx.x * 64 + wv * 16 + m16;
    floatx4 acc[8];
    #pragma unroll
    for (int tt = 0; tt < 8; tt++) acc[tt] = (floatx4){0.f, 0.f, 0.f, 0.f};
    #pragma unroll
    for (int kk = 0; kk < 4; kk++) {
        half8 a = *(const half8*)(A + (size_t)row * 128 + kk * 32 + quad * 8);
        #pragma unroll
        for (int tt = 0; tt < 8; tt++) {
            half8 bf = *(const half8*)(Wt + (size_t)(tt * 16 + m16) * 128 + kk * 32 + quad * 8);
            acc[tt] = __builtin_amdgcn_mfma_f32_16x16x32_f16(a, bf, acc[tt], 0, 0, 0);
        }
    }
    float bias[8];
    #pragma unroll
    for (int tt = 0; tt < 8; tt++)
        bias[tt] = (tt < 4) ? bmu[tt * 16 + m16] : bls[(tt - 4) * 16 + m16];
    int rbase = blockIdx.x * 64 + wv * 16 + quad * 4;
    #pragma unroll
    for (int r = 0; r < 4; r++) {
        int rw = rbase + r;
        if (rw < N_NODES) {
            #pragma unroll
            for (int tt = 0; tt < 4; tt++)
                out[(size_t)rw * 64 + tt * 16 + m16] = acc[tt][r] + bias[tt];
            #pragma unroll
            for (int tt = 4; tt < 8; tt++)
                out[(size_t)N_NODES * 64 + (size_t)rw * 64 + (tt - 4) * 16 + m16] = acc[tt][r] + bias[tt];
        }
    }
}

// ---------------- launch ----------------

extern "C" void kernel_launch(void* const* d_in, const int* in_sizes, int n_in,
                              void* d_out, int out_size, void* d_ws, size_t ws_size,
                              hipStream_t stream) {
    const float* x   = (const float*)d_in[0];
    const int*  eidx = (const int*)d_in[1];
    const float* W1  = (const float*)d_in[2];
    const float* b1  = (const float*)d_in[3];
    const float* Wmu = (const float*)d_in[4];
    const float* bmu = (const float*)d_in[5];
    const float* Wls = (const float*)d_in[6];
    const float* bls = (const float*)d_in[7];
    float* out = (float*)d_out;
    const int* e_src = eidx;
    const int* e_dst = eidx + N_EDGES;

    char* ws = (char*)d_ws;
    size_t off_b = 0;
    auto alloc = [&](size_t n) -> void* {
        void* p = ws + off_b;
        off_b += (n + 255) & ~(size_t)255;
        return p;
    };
    float*  dinv      = (float*)alloc((size_t)N_NODES * sizeof(float));
    int*    row_start = (int*)alloc((size_t)(N_NODES + 1) * sizeof(int));
    int*    btot      = (int*)alloc((size_t)NBUCK * sizeof(int));
    int*    bbase     = (int*)alloc((size_t)(NBUCK + 1) * sizeof(int));
    int*    bcur      = (int*)alloc((size_t)NBUCK * sizeof(int));
    int*    csr_src   = (int*)alloc((size_t)N_EDGES * sizeof(int));
    int*    binned    = (int*)alloc((size_t)N_EDGES * sizeof(int));
    __half* W1t       = (__half*)alloc((size_t)128 * 128 * sizeof(__half));
    __half* Wct       = (__half*)alloc((size_t)128 * 128 * sizeof(__half));
    __half* xs        = (__half*)alloc((size_t)N_NODES * IN_CH * sizeof(__half));  // reused as y2
    __half* bufA      = (__half*)alloc((size_t)N_NODES * HID * sizeof(__half));    // y1
    __half* bufH      = (__half*)alloc((size_t)N_NODES * HID * sizeof(__half));    // hs = dinv*h
    alloc(32 * 1024);  // pad for OOB tile reads in last GEMM block
    __half* bufB = xs;  // xs dead after agg1

    const int NGEMM = (N_NODES + 63) / 64;  // 1563

    // CSR build: hist(atomic totals) -> bases(1-block scan) -> binscatter(reserve+scatter) -> bucket
    hipMemsetAsync(btot, 0, (size_t)NBUCK * sizeof(int), stream);
    hipLaunchKernelGGL(k_hist, dim3(BBLK), dim3(256), 0, stream, e_dst, btot);
    hipLaunchKernelGGL(k_bases, dim3(1), dim3(1024), 0, stream, btot, bbase, bcur);
    hipLaunchKernelGGL(k_binscatter, dim3(BBLK), dim3(256), 0, stream, e_src, e_dst, bcur, binned);
    hipLaunchKernelGGL(k_bucket, dim3(NBUCK), dim3(256), 0, stream, binned, bbase,
                       row_start, dinv, csr_src);
    // xs = fp16(dinv * x) row-major, + folded weight prep (needs dinv)
    hipLaunchKernelGGL(k_cast_prep, dim3(12500 + 64), dim3(256), 0, stream, x, dinv, xs,
                       W1, Wmu, Wls, W1t, Wct);
    // layer 1
    hipLaunchKernelGGL(k_agg, dim3(N_NODES / 4), dim3(256), 0, stream, xs, bufA, csr_src, row_start, dinv);
    hipLaunchKernelGGL(k_gemm1, dim3(NGEMM), dim3(256), 0, stream, bufA, W1t, b1, dinv, bufH);
    // shared aggregation for layers 2+3
    hipLaunchKernelGGL(k_agg, dim3(N_NODES / 4), dim3(256), 0, stream, bufH, bufB, csr_src, row_start, dinv);
    hipLaunchKernelGGL(k_gemm2, dim3(NGEMM), dim3(256), 0, stream, bufB, Wct, bmu, bls, out);
}